// Round 1
// baseline (328.631 us; speedup 1.0000x reference)
//
#include <hip/hip_runtime.h>
#include <hip/hip_bf16.h>
#include <math.h>

// Problem constants
#define B_ 4
#define C_ 256
#define H_ 64
#define W_ 64
#define COMP_ 64
#define KUP_ 5
#define K2_ 25
#define S2_ 4
#define KENC_ 3
#define HW_ (H_*W_)   // 4096
#define EPS_ 1e-5f

// ---------------------------------------------------------------------------
// Kernel T: transpose weights into scalar-load-friendly layouts.
//   wTc[c*64+o]                      = w_comp[o*256+c]
//   wTe[((o*9+q)*4+s2)*25+k2]       = w_enc[((k2*4+s2)*64+o)*9+q]
// ---------------------------------------------------------------------------
__global__ void k_transpose(const float* __restrict__ w_comp,
                            const float* __restrict__ w_enc,
                            float* __restrict__ wTc,
                            float* __restrict__ wTe) {
    int t = blockIdx.x * 256 + threadIdx.x;
    if (t < COMP_ * C_) {
        int o = t & 63;
        int c = t >> 6;
        wTc[t] = w_comp[o * C_ + c];
    } else {
        int t2 = t - COMP_ * C_;
        if (t2 < 100 * COMP_ * 9) {
            int k2 = t2 % 25;
            int r = t2 / 25;
            int s2 = r & 3; r >>= 2;
            int q = r % 9;
            int o = r / 9;
            wTe[t2] = w_enc[(((k2 * 4 + s2) * COMP_) + o) * 9 + q];
        }
    }
}

// ---------------------------------------------------------------------------
// Kernel A: 1x1 compression conv (C=256 -> 64) + BN(eval) + SiLU.
// grid (64 tiles of 64 px, B), block 256 = 64 px * 4 k-groups (one wave each).
// Each thread: 64-channel partial GEMM over its k-slice, LDS reduce, BN+SiLU.
// Weight reads are wave-uniform -> scalar loads.
// ---------------------------------------------------------------------------
__global__ void __launch_bounds__(256)
k_compress(const float* __restrict__ x, const float* __restrict__ wTc,
           const float* __restrict__ gamma, const float* __restrict__ beta,
           const float* __restrict__ mean, const float* __restrict__ var,
           float* __restrict__ act) {
    __shared__ float lds[4][COMP_][64];   // 64 KB: [grp][o][px]
    const int tid = threadIdx.x;
    const int px = tid & 63;
    const int grp = tid >> 6;                       // wave id, uniform per wave
    const int grpu = __builtin_amdgcn_readfirstlane(grp);
    const int b = blockIdx.y;
    const int p0 = blockIdx.x * 64;
    const int p = p0 + px;

    float acc[COMP_];
#pragma unroll
    for (int o = 0; o < COMP_; ++o) acc[o] = 0.f;

    const float* xb = x + (size_t)b * C_ * HW_ + p;
#pragma unroll 4
    for (int cl = 0; cl < 64; ++cl) {
        int c = grpu * 64 + cl;                      // uniform
        float xv = xb[c * HW_];
        const float* w = wTc + c * COMP_;            // uniform ptr -> s_load
#pragma unroll
        for (int o = 0; o < COMP_; ++o)
            acc[o] = fmaf(w[o], xv, acc[o]);
    }

#pragma unroll
    for (int o = 0; o < COMP_; ++o) lds[grp][o][px] = acc[o];
    __syncthreads();

    // reduce 4 partials, BN + SiLU, store. 16 o's per thread.
    const int px2 = tid & 63;
    const int oc = tid >> 6;
#pragma unroll
    for (int k = 0; k < 16; ++k) {
        int o = oc * 16 + k;
        float s = lds[0][o][px2] + lds[1][o][px2] + lds[2][o][px2] + lds[3][o][px2];
        float iv = gamma[o] * rsqrtf(var[o] + EPS_);
        float bn = (s - mean[o]) * iv + beta[o];
        float sg = 1.f / (1.f + __expf(-bn));
        act[((b * COMP_ + o) * HW_) + p0 + px2] = bn * sg;
    }
}

// ---------------------------------------------------------------------------
// Kernel B: 3x3 encoder conv (64 -> 100 ch) + softmax over the 25 k2 channels.
// grid (64 rows i, B), block (64 j, 4 s2). Thread (j,s2) computes all 25 k2
// logits for its softmax group in registers -> softmax -> store.
// act rows i-1..i+1 staged in LDS with column halo; weights scalar-loaded.
// ---------------------------------------------------------------------------
__global__ void __launch_bounds__(256)
k_encoder(const float* __restrict__ act, const float* __restrict__ wTe,
          float* __restrict__ mask) {
    __shared__ float sact[3 * COMP_ * 66];          // 50.7 KB: [row][o][col(=gj+1)]
    const int tx = threadIdx.x;                     // j
    const int ty = threadIdx.y;                     // s2
    const int tid = ty * 64 + tx;
    const int i = blockIdx.x;
    const int b = blockIdx.y;
    const int s2u = __builtin_amdgcn_readfirstlane(ty);

    // cooperative staging with zero halo
    const float* ab = act + (size_t)b * COMP_ * HW_;
    for (int t = tid; t < 3 * COMP_ * 66; t += 256) {
        int col = t % 66;
        int r = t / 66;
        int o = r & 63;
        int row = r >> 6;                            // 0..2
        int gi = i + row - 1;
        int gj = col - 1;
        float v = 0.f;
        if ((unsigned)gi < 64u && (unsigned)gj < 64u)
            v = ab[(o * H_ + gi) * W_ + gj];
        sact[t] = v;
    }
    __syncthreads();

    float acc[K2_];
#pragma unroll
    for (int k = 0; k < K2_; ++k) acc[k] = 0.f;

    for (int o = 0; o < COMP_; ++o) {
#pragma unroll
        for (int q = 0; q < 9; ++q) {
            const int dy = q / 3, dx = q % 3;
            float a = sact[(dy * COMP_ + o) * 66 + tx + dx];
            const float* w = wTe + ((o * 9 + q) * 4 + s2u) * 25;  // uniform
#pragma unroll
            for (int k = 0; k < K2_; ++k)
                acc[k] = fmaf(w[k], a, acc[k]);
        }
    }

    // softmax over the 25 logits
    float mx = acc[0];
#pragma unroll
    for (int k = 1; k < K2_; ++k) mx = fmaxf(mx, acc[k]);
    float sum = 0.f;
#pragma unroll
    for (int k = 0; k < K2_; ++k) { acc[k] = __expf(acc[k] - mx); sum += acc[k]; }
    float rs = 1.f / sum;

    float* mb = mask + (size_t)b * 100 * HW_ + i * W_ + tx;
#pragma unroll
    for (int k = 0; k < K2_; ++k)
        mb[(k * 4 + ty) * HW_] = acc[k] * rs;
}

// ---------------------------------------------------------------------------
// Kernel C: content-aware reassembly + pixel shuffle.
// grid (64 rows i, 16 c-chunks, B), block (64 j, 4 csub); each thread handles
// 4 channels x 4 sub-pixels for one low-res pixel. Mask row staged in LDS.
// out[b,c,2i+s0,2j+s1] = sum_k2 mask[b,k2*4+s2,i,j] * x[b,c,i+dy-2,j+dx-2]
// ---------------------------------------------------------------------------
__global__ void __launch_bounds__(256)
k_reassemble(const float* __restrict__ x, const float* __restrict__ mask,
             float* __restrict__ out) {
    __shared__ float smask[100 * 64];               // 25.6 KB: [ch][j]
    const int tx = threadIdx.x;                     // j
    const int ty = threadIdx.y;                     // csub
    const int tid = ty * 64 + tx;
    const int i = blockIdx.x;
    const int cc = blockIdx.y;
    const int b = blockIdx.z;

    const float* mrow = mask + (size_t)b * 100 * HW_ + i * W_;
    for (int t = tid; t < 100 * 64; t += 256) {
        int ch = t >> 6, jj = t & 63;
        smask[t] = mrow[ch * HW_ + jj];
    }
    __syncthreads();

    const int cbase = cc * 16 + ty * 4;
    const float* xb = x + (size_t)b * C_ * HW_;

    float acc[4][4];
#pragma unroll
    for (int cl = 0; cl < 4; ++cl)
#pragma unroll
        for (int s = 0; s < 4; ++s) acc[cl][s] = 0.f;

#pragma unroll
    for (int k2 = 0; k2 < K2_; ++k2) {
        const int dy = k2 / 5, dx = k2 % 5;
        int ri = i + dy - 2;
        int cj = tx + dx - 2;
        bool ok = ((unsigned)ri < 64u) && ((unsigned)cj < 64u);
        float m0 = smask[(k2 * 4 + 0) * 64 + tx];
        float m1 = smask[(k2 * 4 + 1) * 64 + tx];
        float m2 = smask[(k2 * 4 + 2) * 64 + tx];
        float m3 = smask[(k2 * 4 + 3) * 64 + tx];
#pragma unroll
        for (int cl = 0; cl < 4; ++cl) {
            int c = cbase + cl;
            float xv = ok ? xb[c * HW_ + ri * W_ + cj] : 0.f;
            acc[cl][0] = fmaf(xv, m0, acc[cl][0]);
            acc[cl][1] = fmaf(xv, m1, acc[cl][1]);
            acc[cl][2] = fmaf(xv, m2, acc[cl][2]);
            acc[cl][3] = fmaf(xv, m3, acc[cl][3]);
        }
    }

#pragma unroll
    for (int cl = 0; cl < 4; ++cl) {
        int c = cbase + cl;
        float* op = out + (((size_t)(b * C_ + c) * 128 + 2 * i) * 128) + 2 * tx;
        *(float2*)op         = float2{acc[cl][0], acc[cl][1]};
        *(float2*)(op + 128) = float2{acc[cl][2], acc[cl][3]};
    }
}

// ---------------------------------------------------------------------------
extern "C" void kernel_launch(void* const* d_in, const int* in_sizes, int n_in,
                              void* d_out, int out_size, void* d_ws, size_t ws_size,
                              hipStream_t stream) {
    const float* x       = (const float*)d_in[0];
    const float* w_comp  = (const float*)d_in[1];
    const float* bn_g    = (const float*)d_in[2];
    const float* bn_b    = (const float*)d_in[3];
    const float* bn_m    = (const float*)d_in[4];
    const float* bn_v    = (const float*)d_in[5];
    const float* w_enc   = (const float*)d_in[6];
    float* out = (float*)d_out;

    float* ws   = (float*)d_ws;
    float* wTc  = ws;                       // 16384
    float* wTe  = ws + 16384;               // 57600
    float* act  = ws + 16384 + 57600;       // 1,048,576
    float* mask = act + (size_t)B_ * COMP_ * HW_;  // 1,638,400

    k_transpose<<<289, 256, 0, stream>>>(w_comp, w_enc, wTc, wTe);
    k_compress<<<dim3(64, B_), 256, 0, stream>>>(x, wTc, bn_g, bn_b, bn_m, bn_v, act);
    k_encoder<<<dim3(64, B_), dim3(64, 4), 0, stream>>>(act, wTe, mask);
    k_reassemble<<<dim3(64, 16, B_), dim3(64, 4), 0, stream>>>(x, mask, out);
}

// Round 2
// 238.533 us; speedup vs baseline: 1.3777x; 1.3777x over previous
//
#include <hip/hip_runtime.h>
#include <hip/hip_bf16.h>
#include <math.h>

// Problem constants
#define B_ 4
#define C_ 256
#define H_ 64
#define W_ 64
#define COMP_ 64
#define K2_ 25
#define HW_ (H_*W_)   // 4096
#define EPS_ 1e-5f

// ---------------------------------------------------------------------------
// Kernel T: transpose weights into scalar-load-friendly layouts.
//   wTc[c*64+o]                = w_comp[o*256+c]
//   wTe[((o*9+q)*4+s2)*25+k2]  = w_enc[((k2*4+s2)*64+o)*9+q]
// ---------------------------------------------------------------------------
__global__ void k_transpose(const float* __restrict__ w_comp,
                            const float* __restrict__ w_enc,
                            float* __restrict__ wTc,
                            float* __restrict__ wTe) {
    int t = blockIdx.x * 256 + threadIdx.x;
    if (t < COMP_ * C_) {
        int o = t & 63;
        int c = t >> 6;
        wTc[t] = w_comp[o * C_ + c];
    } else {
        int t2 = t - COMP_ * C_;
        if (t2 < 100 * COMP_ * 9) {
            int k2 = t2 % 25;
            int r = t2 / 25;
            int s2 = r & 3; r >>= 2;
            int q = r % 9;
            int o = r / 9;
            wTe[t2] = w_enc[(((k2 * 4 + s2) * COMP_) + o) * 9 + q];
        }
    }
}

// ---------------------------------------------------------------------------
// Kernel A: 1x1 compression conv (256->64) + BN + SiLU.
// grid (64 px-tiles, B), block (64 px, 4 og, 2 cg) = 512 thr = 8 waves/CU.
// Thread: 16 outputs (og) over 128 channels (cg); cg=1 dumps partials to LDS,
// cg=0 reduces + BN + SiLU + store. Weights wave-uniform -> scalar loads.
// ---------------------------------------------------------------------------
__global__ void __launch_bounds__(512)
k_compress(const float* __restrict__ x, const float* __restrict__ wTc,
           const float* __restrict__ gamma, const float* __restrict__ beta,
           const float* __restrict__ mean, const float* __restrict__ var,
           float* __restrict__ act) {
    __shared__ float red[COMP_ * 64];              // 16 KB
    const int tx = threadIdx.x;                    // px
    const int ty = threadIdx.y;                    // og
    const int tz = threadIdx.z;                    // cg
    const int ogu = __builtin_amdgcn_readfirstlane(ty);
    const int cgu = __builtin_amdgcn_readfirstlane(tz);
    const int b = blockIdx.y;
    const int p0 = blockIdx.x * 64;

    float acc[16];
#pragma unroll
    for (int k = 0; k < 16; ++k) acc[k] = 0.f;

    const float* xb = x + (size_t)b * C_ * HW_ + p0 + tx;
#pragma unroll 4
    for (int cl = 0; cl < 128; ++cl) {
        int c = cgu * 128 + cl;                    // uniform
        float xv = xb[c * HW_];
        const float* w = wTc + c * COMP_ + ogu * 16;  // uniform -> s_load
#pragma unroll
        for (int k = 0; k < 16; ++k)
            acc[k] = fmaf(w[k], xv, acc[k]);
    }

    if (tz == 1) {
#pragma unroll
        for (int k = 0; k < 16; ++k)
            red[(ty * 16 + k) * 64 + tx] = acc[k];
    }
    __syncthreads();
    if (tz == 0) {
#pragma unroll
        for (int k = 0; k < 16; ++k) {
            int o = ty * 16 + k;
            float s = acc[k] + red[o * 64 + tx];
            float iv = gamma[o] * rsqrtf(var[o] + EPS_);
            float bn = (s - mean[o]) * iv + beta[o];
            float sg = 1.f / (1.f + __expf(-bn));
            act[((b * COMP_ + o) * HW_) + p0 + tx] = bn * sg;
        }
    }
}

// ---------------------------------------------------------------------------
// Kernel B: 3x3 encoder conv (64 -> 100 ch) + softmax over 25 k2 channels.
// grid (64 i, B), block (64 j, 4 s2, 2 cg) = 512 thr. Thread (j,s2,cg)
// computes 25 logits over its 32-channel half; LDS reduce (reusing sact);
// cg=0 does softmax + store. Weights wave-uniform -> scalar loads.
// ---------------------------------------------------------------------------
__global__ void __launch_bounds__(512)
k_encoder(const float* __restrict__ act, const float* __restrict__ wTe,
          float* __restrict__ mask) {
    __shared__ float sact[3 * COMP_ * 66];         // 50.7 KB; reused as red[25*256]
    const int tx = threadIdx.x;                    // j
    const int ty = threadIdx.y;                    // s2
    const int tz = threadIdx.z;                    // cg
    const int tid = (tz * 4 + ty) * 64 + tx;
    const int i = blockIdx.x;
    const int b = blockIdx.y;
    const int s2u = __builtin_amdgcn_readfirstlane(ty);
    const int cgu = __builtin_amdgcn_readfirstlane(tz);

    // stage act rows i-1..i+1 with zero halo: [row][o][col(=gj+1)]
    const float* ab = act + (size_t)b * COMP_ * HW_;
    for (int t = tid; t < 3 * COMP_ * 66; t += 512) {
        int col = t % 66;
        int r = t / 66;
        int o = r & 63;
        int row = r >> 6;
        int gi = i + row - 1;
        int gj = col - 1;
        float v = 0.f;
        if ((unsigned)gi < 64u && (unsigned)gj < 64u)
            v = ab[(o * H_ + gi) * W_ + gj];
        sact[t] = v;
    }
    __syncthreads();

    float acc[K2_];
#pragma unroll
    for (int k = 0; k < K2_; ++k) acc[k] = 0.f;

#pragma unroll 1
    for (int oi = 0; oi < 32; ++oi) {
        int o = cgu * 32 + oi;                     // uniform
#pragma unroll
        for (int q = 0; q < 9; ++q) {
            const int dy = q / 3, dx = q % 3;
            float a = sact[(dy * COMP_ + o) * 66 + tx + dx];
            const float* w = wTe + ((o * 9 + q) * 4 + s2u) * 25;  // uniform
#pragma unroll
            for (int k = 0; k < K2_; ++k)
                acc[k] = fmaf(w[k], a, acc[k]);
        }
    }
    __syncthreads();                               // all sact reads done

    float* red = sact;                             // reuse
    if (tz == 1) {
#pragma unroll
        for (int k = 0; k < K2_; ++k)
            red[k * 256 + ty * 64 + tx] = acc[k];
    }
    __syncthreads();
    if (tz == 0) {
#pragma unroll
        for (int k = 0; k < K2_; ++k)
            acc[k] += red[k * 256 + ty * 64 + tx];

        float mx = acc[0];
#pragma unroll
        for (int k = 1; k < K2_; ++k) mx = fmaxf(mx, acc[k]);
        float sum = 0.f;
#pragma unroll
        for (int k = 0; k < K2_; ++k) { acc[k] = __expf(acc[k] - mx); sum += acc[k]; }
        float rs = 1.f / sum;

        float* mb = mask + (size_t)b * 100 * HW_ + i * W_ + tx;
#pragma unroll
        for (int k = 0; k < K2_; ++k)
            mb[(k * 4 + ty) * HW_] = acc[k] * rs;
    }
}

// ---------------------------------------------------------------------------
// Kernel C: content-aware reassembly + pixel shuffle, fully LDS-staged.
// grid (64 i, 16 cc, B), block (64 j, 4 ty). Thread: 4 channels x 4 subpx.
// x tile (16ch x 5rows x 68cols, halo pre-zeroed) + mask row [s][k2][j] in LDS
// -> inner loop is pure conflict-free LDS reads + fma, no bounds checks.
// ---------------------------------------------------------------------------
__global__ void __launch_bounds__(256)
k_reassemble(const float* __restrict__ x, const float* __restrict__ mask,
             float* __restrict__ out) {
    __shared__ float smask[4 * K2_ * 64];          // [s][k2][j]  25.6 KB
    __shared__ float sx[16 * 5 * 68];              // [ch][r][col] 21.8 KB
    const int tx = threadIdx.x;                    // j
    const int ty = threadIdx.y;
    const int tid = ty * 64 + tx;
    const int i = blockIdx.x;
    const int cc = blockIdx.y;
    const int b = blockIdx.z;

    // mask row: global coalesced read, conflict-free LDS write
    const float* mrow = mask + (size_t)b * 100 * HW_ + i * W_;
#pragma unroll 1
    for (int k2 = 0; k2 < K2_; ++k2)
        smask[(ty * K2_ + k2) * 64 + tx] = mrow[(k2 * 4 + ty) * HW_ + tx];

    // x tile with zeroed halo
    const float* xb = x + ((size_t)b * C_ + cc * 16) * HW_;
    for (int t = tid; t < 16 * 5 * 68; t += 256) {
        int ch = t / 340;
        int rem = t - ch * 340;
        int r = rem / 68;
        int col = rem - r * 68;
        int gi = i + r - 2;
        int gj = col - 2;
        float v = 0.f;
        if ((unsigned)gi < 64u && (unsigned)gj < 64u)
            v = xb[ch * HW_ + gi * W_ + gj];
        sx[t] = v;
    }
    __syncthreads();

    float acc[4][4];
#pragma unroll
    for (int cl = 0; cl < 4; ++cl)
#pragma unroll
        for (int s = 0; s < 4; ++s) acc[cl][s] = 0.f;

#pragma unroll
    for (int r = 0; r < 5; ++r) {
        float xv[4][5];
#pragma unroll
        for (int cl = 0; cl < 4; ++cl)
#pragma unroll
            for (int d = 0; d < 5; ++d)
                xv[cl][d] = sx[(ty * 4 + cl) * 340 + r * 68 + tx + d];
#pragma unroll
        for (int dx = 0; dx < 5; ++dx) {
            int k2 = r * 5 + dx;
            float m0 = smask[(0 * K2_ + k2) * 64 + tx];
            float m1 = smask[(1 * K2_ + k2) * 64 + tx];
            float m2 = smask[(2 * K2_ + k2) * 64 + tx];
            float m3 = smask[(3 * K2_ + k2) * 64 + tx];
#pragma unroll
            for (int cl = 0; cl < 4; ++cl) {
                acc[cl][0] = fmaf(xv[cl][dx], m0, acc[cl][0]);
                acc[cl][1] = fmaf(xv[cl][dx], m1, acc[cl][1]);
                acc[cl][2] = fmaf(xv[cl][dx], m2, acc[cl][2]);
                acc[cl][3] = fmaf(xv[cl][dx], m3, acc[cl][3]);
            }
        }
    }

#pragma unroll
    for (int cl = 0; cl < 4; ++cl) {
        int c = cc * 16 + ty * 4 + cl;
        float* op = out + (((size_t)(b * C_ + c) * 128 + 2 * i) * 128) + 2 * tx;
        *(float2*)op         = float2{acc[cl][0], acc[cl][1]};
        *(float2*)(op + 128) = float2{acc[cl][2], acc[cl][3]};
    }
}

// ---------------------------------------------------------------------------
extern "C" void kernel_launch(void* const* d_in, const int* in_sizes, int n_in,
                              void* d_out, int out_size, void* d_ws, size_t ws_size,
                              hipStream_t stream) {
    const float* x       = (const float*)d_in[0];
    const float* w_comp  = (const float*)d_in[1];
    const float* bn_g    = (const float*)d_in[2];
    const float* bn_b    = (const float*)d_in[3];
    const float* bn_m    = (const float*)d_in[4];
    const float* bn_v    = (const float*)d_in[5];
    const float* w_enc   = (const float*)d_in[6];
    float* out = (float*)d_out;

    float* ws   = (float*)d_ws;
    float* wTc  = ws;                              // 16384 floats
    float* wTe  = ws + 16384;                      // 57600 floats
    float* act  = ws + 16384 + 57600;              // 1,048,576 floats
    float* mask = act + (size_t)B_ * COMP_ * HW_;  // 1,638,400 floats

    k_transpose<<<289, 256, 0, stream>>>(w_comp, w_enc, wTc, wTe);
    k_compress<<<dim3(64, B_), dim3(64, 4, 2), 0, stream>>>(x, wTc, bn_g, bn_b, bn_m, bn_v, act);
    k_encoder<<<dim3(64, B_), dim3(64, 4, 2), 0, stream>>>(act, wTe, mask);
    k_reassemble<<<dim3(64, 16, B_), dim3(64, 4), 0, stream>>>(x, mask, out);
}

// Round 3
// 199.230 us; speedup vs baseline: 1.6495x; 1.1973x over previous
//
#include <hip/hip_runtime.h>
#include <hip/hip_bf16.h>
#include <math.h>

// Problem constants
#define B_ 4
#define C_ 256
#define H_ 64
#define W_ 64
#define COMP_ 64
#define K2_ 25
#define HW_ (H_*W_)   // 4096
#define EPS_ 1e-5f

// ---------------------------------------------------------------------------
// Kernel T: weight layout transforms (scalar-load-friendly).
//   wTc[c*64+o]                = w_comp[o*256+c]
//   wTe[((o*9+q)*4+s2)*25+k2]  = w_enc[((k2*4+s2)*64+o)*9+q]
// ---------------------------------------------------------------------------
__global__ void k_transpose(const float* __restrict__ w_comp,
                            const float* __restrict__ w_enc,
                            float* __restrict__ wTc,
                            float* __restrict__ wTe) {
    int t = blockIdx.x * 256 + threadIdx.x;
    if (t < COMP_ * C_) {
        int o = t & 63;
        int c = t >> 6;
        wTc[t] = w_comp[o * C_ + c];
    } else {
        int t2 = t - COMP_ * C_;
        if (t2 < 100 * COMP_ * 9) {
            int k2 = t2 % 25;
            int r = t2 / 25;
            int s2 = r & 3; r >>= 2;
            int q = r % 9;
            int o = r / 9;
            wTe[t2] = w_enc[(((k2 * 4 + s2) * COMP_) + o) * 9 + q];
        }
    }
}

// ---------------------------------------------------------------------------
// Kernel A: 1x1 compression (256->64) + BN + SiLU.
// grid (64 px-tiles, B), block (64 px, 4 og, 4 cg) = 1024 thr = 16 waves.
// Thread: 16 outputs over 64 channels; 4-way LDS tree reduction.
// ---------------------------------------------------------------------------
__global__ void __launch_bounds__(1024)
k_compress(const float* __restrict__ x, const float* __restrict__ wTc,
           const float* __restrict__ gamma, const float* __restrict__ beta,
           const float* __restrict__ mean, const float* __restrict__ var,
           float* __restrict__ act) {
    __shared__ float redA[COMP_ * 64];             // 16 KB
    __shared__ float redB[COMP_ * 64];             // 16 KB
    const int tx = threadIdx.x;                    // px
    const int ty = threadIdx.y;                    // og
    const int tz = threadIdx.z;                    // cg
    const int ogu = __builtin_amdgcn_readfirstlane(ty);
    const int cgu = __builtin_amdgcn_readfirstlane(tz);
    const int b = blockIdx.y;
    const int p0 = blockIdx.x * 64;

    float acc[16];
#pragma unroll
    for (int k = 0; k < 16; ++k) acc[k] = 0.f;

    const float* xb = x + (size_t)b * C_ * HW_ + p0 + tx;
#pragma unroll 4
    for (int cl = 0; cl < 64; ++cl) {
        int c = cgu * 64 + cl;                     // uniform
        float xv = xb[c * HW_];
        const float* w = wTc + c * COMP_ + ogu * 16;  // uniform -> s_load
#pragma unroll
        for (int k = 0; k < 16; ++k)
            acc[k] = fmaf(w[k], xv, acc[k]);
    }

    // 4-way tree reduction: cg1->A, cg2->B; cg0+=A, cg3+=B; cg3->A; cg0+=A
    if (tz == 1) {
#pragma unroll
        for (int k = 0; k < 16; ++k) redA[(ty * 16 + k) * 64 + tx] = acc[k];
    } else if (tz == 2) {
#pragma unroll
        for (int k = 0; k < 16; ++k) redB[(ty * 16 + k) * 64 + tx] = acc[k];
    }
    __syncthreads();
    if (tz == 0) {
#pragma unroll
        for (int k = 0; k < 16; ++k) acc[k] += redA[(ty * 16 + k) * 64 + tx];
    } else if (tz == 3) {
#pragma unroll
        for (int k = 0; k < 16; ++k) acc[k] += redB[(ty * 16 + k) * 64 + tx];
    }
    __syncthreads();
    if (tz == 3) {
#pragma unroll
        for (int k = 0; k < 16; ++k) redA[(ty * 16 + k) * 64 + tx] = acc[k];
    }
    __syncthreads();
    if (tz == 0) {
#pragma unroll
        for (int k = 0; k < 16; ++k) {
            int o = ty * 16 + k;
            float s = acc[k] + redA[o * 64 + tx];
            float iv = gamma[o] * rsqrtf(var[o] + EPS_);
            float bn = (s - mean[o]) * iv + beta[o];
            float sg = 1.f / (1.f + __expf(-bn));
            act[((b * COMP_ + o) * HW_) + p0 + tx] = bn * sg;
        }
    }
}

// ---------------------------------------------------------------------------
// Kernel B: 3x3 encoder conv (64->100) + softmax(25) + output transpose.
// grid (64 i, B), block (64 j, 4 s2, 4 og) = 1024 thr = 16 waves.
// Thread: 25 logits over its 16-channel quarter; 4-way LDS reduction;
// softmax in og0; in-LDS transpose to [j][100]; coalesced global write to
// maskT[b][i*64+j][100].
// ---------------------------------------------------------------------------
__global__ void __launch_bounds__(1024)
k_encoder(const float* __restrict__ act, const float* __restrict__ wTe,
          float* __restrict__ maskT) {
    __shared__ float sact[12800];                  // 51.2 KB (staging 12672, then 2x6400 bufs)
    const int tx = threadIdx.x;                    // j
    const int ty = threadIdx.y;                    // s2
    const int tz = threadIdx.z;                    // og
    const int tid = (tz * 4 + ty) * 64 + tx;
    const int i = blockIdx.x;
    const int b = blockIdx.y;
    const int s2u = __builtin_amdgcn_readfirstlane(ty);
    const int ogu = __builtin_amdgcn_readfirstlane(tz);

    // stage act rows i-1..i+1 with zero halo: [row][o][col(=gj+1)], 3*64*66
    const float* ab = act + (size_t)b * COMP_ * HW_;
    for (int t = tid; t < 3 * COMP_ * 66; t += 1024) {
        int col = t % 66;
        int r = t / 66;
        int o = r & 63;
        int row = r >> 6;
        int gi = i + row - 1;
        int gj = col - 1;
        float v = 0.f;
        if ((unsigned)gi < 64u && (unsigned)gj < 64u)
            v = ab[(o * H_ + gi) * W_ + gj];
        sact[t] = v;
    }
    __syncthreads();

    float acc[K2_];
#pragma unroll
    for (int k = 0; k < K2_; ++k) acc[k] = 0.f;

#pragma unroll 1
    for (int oi = 0; oi < 16; ++oi) {
        int o = ogu * 16 + oi;                     // uniform
#pragma unroll
        for (int q = 0; q < 9; ++q) {
            const int dy = q / 3, dx = q % 3;
            float a = sact[(dy * COMP_ + o) * 66 + tx + dx];
            const float* w = wTe + ((o * 9 + q) * 4 + s2u) * 25;  // uniform
#pragma unroll
            for (int k = 0; k < K2_; ++k)
                acc[k] = fmaf(w[k], a, acc[k]);
        }
    }
    __syncthreads();                               // sact reads done

    float* bufA = sact;                            // 6400 dw
    float* bufB = sact + 6400;                     // 6400 dw
    const int rix = ty * 64 + tx;                  // 0..255
    if (tz == 1) {
#pragma unroll
        for (int k = 0; k < K2_; ++k) bufA[k * 256 + rix] = acc[k];
    } else if (tz == 2) {
#pragma unroll
        for (int k = 0; k < K2_; ++k) bufB[k * 256 + rix] = acc[k];
    }
    __syncthreads();
    if (tz == 0) {
#pragma unroll
        for (int k = 0; k < K2_; ++k) acc[k] += bufA[k * 256 + rix];
    } else if (tz == 3) {
#pragma unroll
        for (int k = 0; k < K2_; ++k) acc[k] += bufB[k * 256 + rix];
    }
    __syncthreads();
    if (tz == 3) {
#pragma unroll
        for (int k = 0; k < K2_; ++k) bufA[k * 256 + rix] = acc[k];
    }
    __syncthreads();
    if (tz == 0) {
#pragma unroll
        for (int k = 0; k < K2_; ++k) acc[k] += bufA[k * 256 + rix];

        // softmax over 25
        float mx = acc[0];
#pragma unroll
        for (int k = 1; k < K2_; ++k) mx = fmaxf(mx, acc[k]);
        float sum = 0.f;
#pragma unroll
        for (int k = 0; k < K2_; ++k) { acc[k] = __expf(acc[k] - mx); sum += acc[k]; }
        float rs = 1.f / sum;

        // transpose into bufB as [j][k2*4+s2]
#pragma unroll
        for (int k = 0; k < K2_; ++k)
            bufB[tx * 100 + k * 4 + ty] = acc[k] * rs;
    }
    __syncthreads();

    // coalesced write: maskT[b][(i*64+j)*100 + ch]
    float4* dst = (float4*)(maskT + ((size_t)b * HW_ + i * 64) * 100);
    const float4* src = (const float4*)bufB;
    for (int t = tid; t < 1600; t += 1024)
        dst[t] = src[t];
}

// ---------------------------------------------------------------------------
// Kernel C: reassembly + pixel shuffle, all-b128 LDS operands.
// grid (64 i, 16 cc, B), block (64 j, 4 cs). Thread: 4 ch x 4 subpx.
// sx:    [r][col][ch pad 20]  -> ds_read_b128 over 4 channels (conflict-free)
// smask: [j][100]             -> ds_read_b128 over 4 subpx   (conflict-free)
// ---------------------------------------------------------------------------
__global__ void __launch_bounds__(256)
k_reassemble(const float* __restrict__ x, const float* __restrict__ maskT,
             float* __restrict__ out) {
    __shared__ __align__(16) float smask[64 * 100];   // 25.6 KB
    __shared__ __align__(16) float sx[5 * 68 * 20];   // 27.2 KB
    const int tx = threadIdx.x;                    // j
    const int ty = threadIdx.y;                    // ch-sub
    const int tid = ty * 64 + tx;
    const int i = blockIdx.x;
    const int cc = blockIdx.y;
    const int b = blockIdx.z;

    // mask row: fully coalesced float4 copy (6400 dw)
    {
        const float4* src = (const float4*)(maskT + ((size_t)b * HW_ + i * 64) * 100);
        float4* dst = (float4*)smask;
#pragma unroll
        for (int t = 0; t < 7; ++t) {
            int e = tid + t * 256;
            if (e < 1600) dst[e] = src[e];
        }
    }

    // x tile [r][col][ch], zero halo
    const float* xb = x + ((size_t)b * C_ + cc * 16) * HW_;
    for (int e = tid; e < 16 * 340; e += 256) {
        int ch = e / 340;
        int rc = e - ch * 340;
        int r = rc / 68;
        int col = rc - r * 68;
        int gi = i + r - 2;
        int gj = col - 2;
        float v = 0.f;
        if ((unsigned)gi < 64u && (unsigned)gj < 64u)
            v = xb[ch * HW_ + gi * W_ + gj];
        sx[rc * 20 + ch] = v;
    }
    __syncthreads();

    float acc[4][4];
#pragma unroll
    for (int cl = 0; cl < 4; ++cl)
#pragma unroll
        for (int s = 0; s < 4; ++s) acc[cl][s] = 0.f;

#pragma unroll
    for (int r = 0; r < 5; ++r) {
        float4 xq[5];
#pragma unroll
        for (int d = 0; d < 5; ++d)
            xq[d] = *(const float4*)&sx[(r * 68 + tx + d) * 20 + ty * 4];
#pragma unroll
        for (int dx = 0; dx < 5; ++dx) {
            int k2 = r * 5 + dx;
            float4 m = *(const float4*)&smask[tx * 100 + k2 * 4];
            acc[0][0] = fmaf(xq[dx].x, m.x, acc[0][0]);
            acc[0][1] = fmaf(xq[dx].x, m.y, acc[0][1]);
            acc[0][2] = fmaf(xq[dx].x, m.z, acc[0][2]);
            acc[0][3] = fmaf(xq[dx].x, m.w, acc[0][3]);
            acc[1][0] = fmaf(xq[dx].y, m.x, acc[1][0]);
            acc[1][1] = fmaf(xq[dx].y, m.y, acc[1][1]);
            acc[1][2] = fmaf(xq[dx].y, m.z, acc[1][2]);
            acc[1][3] = fmaf(xq[dx].y, m.w, acc[1][3]);
            acc[2][0] = fmaf(xq[dx].z, m.x, acc[2][0]);
            acc[2][1] = fmaf(xq[dx].z, m.y, acc[2][1]);
            acc[2][2] = fmaf(xq[dx].z, m.z, acc[2][2]);
            acc[2][3] = fmaf(xq[dx].z, m.w, acc[2][3]);
            acc[3][0] = fmaf(xq[dx].w, m.x, acc[3][0]);
            acc[3][1] = fmaf(xq[dx].w, m.y, acc[3][1]);
            acc[3][2] = fmaf(xq[dx].w, m.z, acc[3][2]);
            acc[3][3] = fmaf(xq[dx].w, m.w, acc[3][3]);
        }
    }

#pragma unroll
    for (int cl = 0; cl < 4; ++cl) {
        int c = cc * 16 + ty * 4 + cl;
        float* op = out + (((size_t)(b * C_ + c) * 128 + 2 * i) * 128) + 2 * tx;
        *(float2*)op         = float2{acc[cl][0], acc[cl][1]};
        *(float2*)(op + 128) = float2{acc[cl][2], acc[cl][3]};
    }
}

// ---------------------------------------------------------------------------
extern "C" void kernel_launch(void* const* d_in, const int* in_sizes, int n_in,
                              void* d_out, int out_size, void* d_ws, size_t ws_size,
                              hipStream_t stream) {
    const float* x       = (const float*)d_in[0];
    const float* w_comp  = (const float*)d_in[1];
    const float* bn_g    = (const float*)d_in[2];
    const float* bn_b    = (const float*)d_in[3];
    const float* bn_m    = (const float*)d_in[4];
    const float* bn_v    = (const float*)d_in[5];
    const float* w_enc   = (const float*)d_in[6];
    float* out = (float*)d_out;

    float* ws    = (float*)d_ws;
    float* wTc   = ws;                             // 16384 floats
    float* wTe   = ws + 16384;                     // 57600 floats
    float* act   = ws + 16384 + 57600;             // 1,048,576 floats
    float* maskT = act + (size_t)B_ * COMP_ * HW_; // 1,638,400 floats

    k_transpose<<<289, 256, 0, stream>>>(w_comp, w_enc, wTc, wTe);
    k_compress<<<dim3(64, B_), dim3(64, 4, 4), 0, stream>>>(x, wTc, bn_g, bn_b, bn_m, bn_v, act);
    k_encoder<<<dim3(64, B_), dim3(64, 4, 4), 0, stream>>>(act, wTe, maskT);
    k_reassemble<<<dim3(64, 16, B_), dim3(64, 4), 0, stream>>>(x, maskT, out);
}